// Round 2
// baseline (860.626 us; speedup 1.0000x reference)
//
#include <hip/hip_runtime.h>

#define TILE 64
#define BK 16

#define B_ 4
#define T_ 1024
#define NH 12
#define HS 64
#define CDIM 768
#define QKVW 2304   // 3*CDIM

// ---------------- GEMM: C[M,N] = A[M,K] @ B[K,N] (+ R) -----------------
template<bool ADD_RES>
__global__ __launch_bounds__(256)
void gemm64(const float* __restrict__ A, const float* __restrict__ Bm,
            const float* __restrict__ R, float* __restrict__ C,
            int M, int N, int K) {
    __shared__ float As[BK][TILE + 4];
    __shared__ float Bs[BK][TILE];

    const int tid = threadIdx.x;
    const int tm  = tid >> 4;
    const int tn  = tid & 15;
    const int m0  = blockIdx.y * TILE;
    const int n0  = blockIdx.x * TILE;

    const int am = tid >> 2;
    const int ak = (tid & 3) * 4;
    const int bk = tid >> 4;
    const int bn = (tid & 15) * 4;

    const float* Aptr = A + (size_t)(m0 + am) * K + ak;
    const float* Bptr = Bm + (size_t)bk * N + n0 + bn;

    float acc[4][4];
#pragma unroll
    for (int ii = 0; ii < 4; ++ii)
#pragma unroll
        for (int jj = 0; jj < 4; ++jj) acc[ii][jj] = 0.f;

    for (int k0 = 0; k0 < K; k0 += BK) {
        const float4 av = *(const float4*)(Aptr + k0);
        const float4 bv = *(const float4*)(Bptr + (size_t)k0 * N);
        __syncthreads();
        As[ak + 0][am] = av.x;
        As[ak + 1][am] = av.y;
        As[ak + 2][am] = av.z;
        As[ak + 3][am] = av.w;
        *(float4*)&Bs[bk][bn] = bv;
        __syncthreads();
#pragma unroll
        for (int kk = 0; kk < BK; ++kk) {
            const float4 a = *(const float4*)&As[kk][tm * 4];
            const float4 b = *(const float4*)&Bs[kk][tn * 4];
            const float ar[4] = {a.x, a.y, a.z, a.w};
            const float br[4] = {b.x, b.y, b.z, b.w};
#pragma unroll
            for (int ii = 0; ii < 4; ++ii)
#pragma unroll
                for (int jj = 0; jj < 4; ++jj)
                    acc[ii][jj] = fmaf(ar[ii], br[jj], acc[ii][jj]);
        }
    }

#pragma unroll
    for (int ii = 0; ii < 4; ++ii) {
        const int m = m0 + tm * 4 + ii;
        float4 out;
        out.x = acc[ii][0]; out.y = acc[ii][1]; out.z = acc[ii][2]; out.w = acc[ii][3];
        if (ADD_RES) {
            const float4 r = *(const float4*)(R + (size_t)m * N + n0 + tn * 4);
            out.x += r.x; out.y += r.y; out.z += r.z; out.w += r.w;
        }
        *(float4*)(C + (size_t)m * N + n0 + tn * 4) = out;
    }
}

// -------- per-64-element standardization (mean / unbiased std) ----------
__global__ __launch_bounds__(256)
void norm_kernel(float* __restrict__ qkv) {
    const int g    = blockIdx.x * 4 + (threadIdx.x >> 6);
    const int lane = threadIdx.x & 63;
    const size_t idx = (size_t)g * 64 + lane;
    const float v = qkv[idx];
    float s = v, ss = v * v;
#pragma unroll
    for (int off = 1; off < 64; off <<= 1) {
        s  += __shfl_xor(s,  off, 64);
        ss += __shfl_xor(ss, off, 64);
    }
    const float mu  = s * (1.0f / 64.0f);
    const float var = (ss - 64.0f * mu * mu) * (1.0f / 63.0f);
    const float rs  = rsqrtf(var);
    qkv[idx] = (v - mu) * rs;
}

// ----------------------------- scan -------------------------------------
// grid: 48 (b,h) * 4 row-blocks = 192 single-wave blocks.
// Wave layout: lane=(r,cg), r=tid>>2 (16 rows), cg=tid&3 (4 col-groups of 16).
// Step: bu = -b*u; S[z] = 0.99*S[z] + bu*k[z] + ki*v[z];
//       ov += S[z]*q[z]; u_next += S[z]*k_next[z]  (fused next-step dot).
// 4-deep register prefetch pipeline hides L3/HBM latency.
__device__ __forceinline__ void load16(const float* __restrict__ p, float (&d)[16]) {
    const float4 a = *(const float4*)(p + 0);
    const float4 b = *(const float4*)(p + 4);
    const float4 c = *(const float4*)(p + 8);
    const float4 e = *(const float4*)(p + 12);
    d[0]=a.x; d[1]=a.y; d[2]=a.z; d[3]=a.w;
    d[4]=b.x; d[5]=b.y; d[6]=b.z; d[7]=b.w;
    d[8]=c.x; d[9]=c.y; d[10]=c.z; d[11]=c.w;
    d[12]=e.x; d[13]=e.y; d[14]=e.z; d[15]=e.w;
}

__device__ __forceinline__ void load_bufs(const float* __restrict__ p, int j0, int i,
                                          float (&q)[16], float (&k)[16], float (&v)[16],
                                          float& ki) {
    load16(p + j0, q);
    load16(p + CDIM + j0, k);
    load16(p + 2 * CDIM + j0, v);
    ki = p[CDIM + i];
}

__device__ __forceinline__ void scan_step(float (&S)[16], float& uc,
                                          const float (&q)[16], const float (&k)[16],
                                          const float (&v)[16], float ki,
                                          const float (&kn)[16],
                                          float* __restrict__ sp, bool doStore) {
    const float bu = -0.01f * uc;
    float ov0 = 0.f, ov1 = 0.f, un0 = 0.f, un1 = 0.f;
#pragma unroll
    for (int z = 0; z < 16; z += 2) {
        const float sa = fmaf(bu, k[z],   fmaf(ki, v[z],   0.99f * S[z]));
        const float sb = fmaf(bu, k[z+1], fmaf(ki, v[z+1], 0.99f * S[z+1]));
        S[z]   = sa;
        S[z+1] = sb;
        ov0 = fmaf(sa, q[z],    ov0);
        ov1 = fmaf(sb, q[z+1],  ov1);
        un0 = fmaf(sa, kn[z],   un0);
        un1 = fmaf(sb, kn[z+1], un1);
    }
    float ov = ov0 + ov1;
    float un = un0 + un1;
    ov += __shfl_xor(ov, 1, 64);
    un += __shfl_xor(un, 1, 64);
    ov += __shfl_xor(ov, 2, 64);
    un += __shfl_xor(un, 2, 64);
    uc = un;
    if (doStore) *sp = ov;
}

__global__ __launch_bounds__(64, 1)
void scan_kernel(const float* __restrict__ qkv, float* __restrict__ o) {
    const int bh = blockIdx.x >> 2;   // 0..47
    const int rb = blockIdx.x & 3;    // row block 0..3
    const int b  = bh / NH;
    const int h  = bh - b * NH;
    const int tid = threadIdx.x;
    const int r   = tid >> 2;         // 0..15
    const int cg  = tid & 3;          // 0..3
    const int i   = rb * 16 + r;      // state row 0..63
    const int j0  = cg * 16;          // first col of this lane's group

    const float* base = qkv + (size_t)b * T_ * QKVW + h * HS;
    float* sp = o + (size_t)b * T_ * CDIM + h * HS + i;   // + t*CDIM per step
    const bool doStore = (cg == 0);

    float S[16];
#pragma unroll
    for (int z = 0; z < 16; ++z) S[z] = 0.f;

    float q0[16], k0[16], v0[16], ki0;
    float q1[16], k1[16], v1[16], ki1;
    float q2[16], k2[16], v2[16], ki2;
    float q3[16], k3[16], v3[16], ki3;

    load_bufs(base + 0 * QKVW, j0, i, q0, k0, v0, ki0);
    load_bufs(base + 1 * QKVW, j0, i, q1, k1, v1, ki1);
    load_bufs(base + 2 * QKVW, j0, i, q2, k2, v2, ki2);
    load_bufs(base + 3 * QKVW, j0, i, q3, k3, v3, ki3);

    float uc = 0.f;   // u for step 0 is S·k = 0

    for (int t = 0; t < T_; t += 4) {
        scan_step(S, uc, q0, k0, v0, ki0, k1, sp + (size_t)t * CDIM, doStore);
        if (t + 4 < T_) load_bufs(base + (size_t)(t + 4) * QKVW, j0, i, q0, k0, v0, ki0);

        scan_step(S, uc, q1, k1, v1, ki1, k2, sp + (size_t)(t + 1) * CDIM, doStore);
        if (t + 5 < T_) load_bufs(base + (size_t)(t + 5) * QKVW, j0, i, q1, k1, v1, ki1);

        scan_step(S, uc, q2, k2, v2, ki2, k3, sp + (size_t)(t + 2) * CDIM, doStore);
        if (t + 6 < T_) load_bufs(base + (size_t)(t + 6) * QKVW, j0, i, q2, k2, v2, ki2);

        scan_step(S, uc, q3, k3, v3, ki3, k0, sp + (size_t)(t + 3) * CDIM, doStore);
        if (t + 7 < T_) load_bufs(base + (size_t)(t + 7) * QKVW, j0, i, q3, k3, v3, ki3);
    }
}

// ------------------------------ launch ----------------------------------
extern "C" void kernel_launch(void* const* d_in, const int* in_sizes, int n_in,
                              void* d_out, int out_size, void* d_ws, size_t ws_size,
                              hipStream_t stream) {
    const float* x      = (const float*)d_in[0];   // (4,1024,768)
    const float* w_attn = (const float*)d_in[1];   // (768, 2304)
    const float* w_proj = (const float*)d_in[2];   // (768, 768)
    float* out = (float*)d_out;
    float* qkv = (float*)d_ws;                     // 4096 x 2304 fp32
    float* y   = (float*)d_ws;                     // reuse after scan

    const int M = B_ * T_;   // 4096

    gemm64<false><<<dim3(QKVW / TILE, M / TILE), 256, 0, stream>>>(
        x, w_attn, nullptr, qkv, M, QKVW, CDIM);

    norm_kernel<<<(M * 3 * NH) / 4, 256, 0, stream>>>(qkv);

    scan_kernel<<<48 * 4, 64, 0, stream>>>(qkv, out);

    gemm64<true><<<dim3(CDIM / TILE, M / TILE), 256, 0, stream>>>(
        out, w_proj, x, y, M, CDIM, CDIM);

    hipMemcpyAsync(d_out, y, (size_t)M * CDIM * sizeof(float),
                   hipMemcpyDeviceToDevice, stream);
}